// Round 6
// baseline (364.818 us; speedup 1.0000x reference)
//
#include <hip/hip_runtime.h>
#include <cstdint>
#include <cstddef>

// PTFDecoder round 6: round-3 structure with the permlane32_swap direction
// FIXED (dst=y, src=x; ISA: exchange VDST[63:32] <-> VSRC[31:0], so
// y_new=[y_lo,x_lo]=w[0], x_new=[y_hi,x_hi]=w[2]). Weight staging packs RTE.
// Zero-barrier main loop; each wave owns 32 t-columns, computes all 128 rows
// per layer with mfma_f32_32x32x16_f16; layer->layer handoff in-register.

namespace {

constexpr int kJ = 14;
constexpr int kT = 32768;
constexpr int kChunks = 2;          // 256-col chunks per block
constexpr int kSmem = 104448;

typedef _Float16 f16x8 __attribute__((ext_vector_type(8)));
typedef float f32x4 __attribute__((ext_vector_type(4)));
typedef float f32x16 __attribute__((ext_vector_type(16)));

union AccU  { f32x16 v; f32x4 q[4]; float s[16]; };
union FragU { f16x8 v; uint32_t w[4]; };

__device__ __forceinline__ uint32_t pkrtz(float a, float b) {
    auto h = __builtin_amdgcn_cvt_pkrtz(a, b);   // __fp16 ext_vector_type(2)
    return __builtin_bit_cast(uint32_t, h);
}
__device__ __forceinline__ uint32_t pkrte(float a, float b) {
    union { _Float16 h[2]; uint32_t u; } r;
    r.h[0] = (_Float16)a; r.h[1] = (_Float16)b;
    return r.u;
}

__global__ __launch_bounds__(512, 2)
void ptf_kernel(const float* __restrict__ pg,
                const float* __restrict__ cg,
                const float* __restrict__ psg,
                const float* __restrict__ W0g,
                const float* __restrict__ b0g,
                const float* __restrict__ W1g,
                const float* __restrict__ b1g,
                const float* __restrict__ W2g,
                const float* __restrict__ b2g,
                const float* __restrict__ W3g,
                const float* __restrict__ b3g,
                float* __restrict__ outg)
{
    extern __shared__ char smem[];
    // W0c @0, W1 @32768, W2 @65536 : f16 [128 rows][128 k], XOR-swizzled
    char*  const W0p   = smem + 98304;            // f16 [128][16] (p0,p1,p2,b0,0..)
    float* const blds1 = (float*)(smem + 102400); // [128] acc-layout b1
    float* const blds2 = (float*)(smem + 102912); // [128] acc-layout b2
    float* const w3t   = (float*)(smem + 103424); // [128] acc-layout W3

    const int tid  = threadIdx.x;
    const int lane = tid & 63;
    const int wv   = tid >> 6;       // wave 0..7
    const int lr5  = lane & 31;      // t within wave-tile / matrix col
    const int hi   = lane >> 5;

    const int bid  = blockIdx.x;
    const int pair = bid % 28;
    const int j    = pair % kJ;
    const int b    = pair / kJ;
    const int cbase = (bid / 28) * (kChunks * 256);

    // ---------------- stage weights into LDS (RTE packs) ----------------
    {
        const int r  = tid >> 2;     // 0..127
        const int kq = tid & 3;      // 0..3 -> k = kq*32..+31
        const uint32_t sw = (uint32_t)((r & 7) << 4);
        const float* s0 = W0g + (size_t)(j * 128 + r) * 131 + 3 + kq * 32;
        const float* s1 = W1g + (size_t)(j * 128 + r) * 128 + kq * 32;
        const float* s2 = W2g + (size_t)(j * 128 + r) * 128 + kq * 32;
#pragma unroll
        for (int s = 0; s < 4; ++s) {
            const uint32_t off = (uint32_t)(r * 256 + kq * 64 + s * 16) ^ sw;
            {   // W0 c-part (unaligned stride 131 -> scalar loads)
                FragU f;
                f.w[0] = pkrte(s0[s*8+0], s0[s*8+1]);
                f.w[1] = pkrte(s0[s*8+2], s0[s*8+3]);
                f.w[2] = pkrte(s0[s*8+4], s0[s*8+5]);
                f.w[3] = pkrte(s0[s*8+6], s0[s*8+7]);
                *(f16x8*)(smem + off) = f.v;
            }
            {
                f32x4 a = *(const f32x4*)(s1 + s * 8);
                f32x4 c = *(const f32x4*)(s1 + s * 8 + 4);
                FragU f;
                f.w[0] = pkrte(a[0], a[1]); f.w[1] = pkrte(a[2], a[3]);
                f.w[2] = pkrte(c[0], c[1]); f.w[3] = pkrte(c[2], c[3]);
                *(f16x8*)(smem + 32768 + off) = f.v;
            }
            {
                f32x4 a = *(const f32x4*)(s2 + s * 8);
                f32x4 c = *(const f32x4*)(s2 + s * 8 + 4);
                FragU f;
                f.w[0] = pkrte(a[0], a[1]); f.w[1] = pkrte(a[2], a[3]);
                f.w[2] = pkrte(c[0], c[1]); f.w[3] = pkrte(c[2], c[3]);
                *(f16x8*)(smem + 65536 + off) = f.v;
            }
        }
    }
    if (tid < 128) {
        const size_t jr = (size_t)(j * 128 + tid);
        FragU f;
        f.w[0] = pkrte(W0g[jr * 131 + 0], W0g[jr * 131 + 1]);
        f.w[1] = pkrte(W0g[jr * 131 + 2], b0g[j * 128 + tid]);
        f.w[2] = 0; f.w[3] = 0;
        *(f16x8*)(W0p + tid * 32) = f.v;
        FragU z; z.w[0] = z.w[1] = z.w[2] = z.w[3] = 0;
        *(f16x8*)(W0p + tid * 32 + 16) = z.v;
        // acc-layout tables: tid = m*32 + h2*16 + reg
        const int m  = tid >> 5;
        const int h2 = (tid >> 4) & 1;
        const int rg = tid & 15;
        const int rr = 32 * m + (rg & 3) + 8 * (rg >> 2) + 4 * h2;
        blds1[tid] = b1g[j * 128 + rr];
        blds2[tid] = b2g[j * 128 + rr];
        w3t[tid]   = W3g[j * 128 + rr];
    }
    const float b3v = b3g[j];
    __syncthreads();   // last barrier in the kernel

    // relu + f32->f16 pack + permlane32_swap: acc -> next-layer B-frags
    // Need: w[0]=[y_lo,x_lo], w[2]=[y_hi,x_hi]  (y=regs 8k1+{0,1}, x=+4)
    // v_permlane32_swap_b32 dst,src exchanges dst[63:32] <-> src[31:0]:
    //   dst_new=[dst_lo,src_lo], src_new=[dst_hi,src_hi]  => dst=y, src=x.
    auto transition = [&](AccU (&A)[4], FragU (&h)[8]) {
#pragma unroll
        for (int m = 0; m < 4; ++m)
#pragma unroll
            for (int k = 0; k < 16; ++k) A[m].s[k] = fmaxf(A[m].s[k], 0.0f);
#pragma unroll
        for (int kk = 0; kk < 8; ++kk) {
            const int m  = kk >> 1;
            const int k1 = kk & 1;
            uint32_t y0 = pkrtz(A[m].s[(2*k1)*4 + 0], A[m].s[(2*k1)*4 + 1]);
            uint32_t x0 = pkrtz(A[m].s[(2*k1+1)*4 + 0], A[m].s[(2*k1+1)*4 + 1]);
            asm volatile("v_permlane32_swap_b32 %0, %1" : "+v"(y0), "+v"(x0));
            h[kk].w[0] = y0; h[kk].w[2] = x0;
            uint32_t y1 = pkrtz(A[m].s[(2*k1)*4 + 2], A[m].s[(2*k1)*4 + 3]);
            uint32_t x1 = pkrtz(A[m].s[(2*k1+1)*4 + 2], A[m].s[(2*k1+1)*4 + 3]);
            asm volatile("v_permlane32_swap_b32 %0, %1" : "+v"(y1), "+v"(x1));
            h[kk].w[1] = y1; h[kk].w[3] = x1;
        }
    };

    // ---------------- main loop: no barriers ----------------
    for (int ch = 0; ch < kChunks; ++ch) {
        const int tg = cbase + ch * 256 + wv * 32 + lr5;

        // x: B-frag raw loads (k = kk*16 + hi*8 + e), coalesced over lr5
        float xr[64];
#pragma unroll
        for (int kk = 0; kk < 8; ++kk)
#pragma unroll
            for (int e = 0; e < 8; ++e)
                xr[kk*8+e] = cg[(size_t)(b * 128 + kk * 16 + hi * 8 + e) * kT + tg];
        const float p0 = pg[(size_t)(b * 42 + j * 3 + 0) * kT + tg];
        const float p1 = pg[(size_t)(b * 42 + j * 3 + 1) * kT + tg];
        const float p2 = pg[(size_t)(b * 42 + j * 3 + 2) * kT + tg];
        const float psv = psg[(size_t)(b * kJ + j) * kT + tg];

        AccU acc[4];
#pragma unroll
        for (int m = 0; m < 4; ++m)
#pragma unroll
            for (int k = 0; k < 16; ++k) acc[m].s[k] = 0.0f;

        // ---- layer 0: 9th K-tile carries [p0,p1,p2,1]*[W0p|b0]
        {
            FragU bp;
            bp.w[0] = hi ? 0u : pkrte(p0, p1);
            bp.w[1] = hi ? 0u : pkrte(p2, 1.0f);
            bp.w[2] = 0; bp.w[3] = 0;
#pragma unroll
            for (int m = 0; m < 4; ++m) {
                f16x8 a = *(const f16x8*)(W0p + (32 * m + lr5) * 32 + hi * 16);
                acc[m].v = __builtin_amdgcn_mfma_f32_32x32x16_f16(a, bp.v, acc[m].v, 0, 0, 0);
            }
        }
#pragma unroll
        for (int kk = 0; kk < 8; ++kk) {
            FragU bx;
            bx.w[0] = pkrtz(xr[kk*8+0], xr[kk*8+1]);
            bx.w[1] = pkrtz(xr[kk*8+2], xr[kk*8+3]);
            bx.w[2] = pkrtz(xr[kk*8+4], xr[kk*8+5]);
            bx.w[3] = pkrtz(xr[kk*8+6], xr[kk*8+7]);
#pragma unroll
            for (int m = 0; m < 4; ++m) {
                const int row = 32 * m + lr5;
                const uint32_t off = (uint32_t)(row * 256 + kk * 32 + hi * 16)
                                     ^ (uint32_t)((lr5 & 7) << 4);
                f16x8 a = *(const f16x8*)(smem + off);
                acc[m].v = __builtin_amdgcn_mfma_f32_32x32x16_f16(a, bx.v, acc[m].v, 0, 0, 0);
            }
        }

        FragU hfr[8];
        transition(acc, hfr);

        // ---- layer 1 (bias via broadcast acc-init)
#pragma unroll
        for (int m = 0; m < 4; ++m)
#pragma unroll
            for (int q = 0; q < 4; ++q)
                acc[m].q[q] = *(const f32x4*)((const char*)blds1 + m * 128 + hi * 64 + q * 16);
#pragma unroll
        for (int kk = 0; kk < 8; ++kk)
#pragma unroll
            for (int m = 0; m < 4; ++m) {
                const int row = 32 * m + lr5;
                const uint32_t off = (uint32_t)(row * 256 + kk * 32 + hi * 16)
                                     ^ (uint32_t)((lr5 & 7) << 4);
                f16x8 a = *(const f16x8*)(smem + 32768 + off);
                acc[m].v = __builtin_amdgcn_mfma_f32_32x32x16_f16(a, hfr[kk].v, acc[m].v, 0, 0, 0);
            }

        transition(acc, hfr);

        // ---- layer 2
#pragma unroll
        for (int m = 0; m < 4; ++m)
#pragma unroll
            for (int q = 0; q < 4; ++q)
                acc[m].q[q] = *(const f32x4*)((const char*)blds2 + m * 128 + hi * 64 + q * 16);
#pragma unroll
        for (int kk = 0; kk < 8; ++kk)
#pragma unroll
            for (int m = 0; m < 4; ++m) {
                const int row = 32 * m + lr5;
                const uint32_t off = (uint32_t)(row * 256 + kk * 32 + hi * 16)
                                     ^ (uint32_t)((lr5 & 7) << 4);
                f16x8 a = *(const f16x8*)(smem + 65536 + off);
                acc[m].v = __builtin_amdgcn_mfma_f32_32x32x16_f16(a, hfr[kk].v, acc[m].v, 0, 0, 0);
            }

        // ---- epilogue: o = relu(h2) . W3 + b3 ; out += o*ps/J
        float ssum = 0.0f;
#pragma unroll
        for (int m = 0; m < 4; ++m)
#pragma unroll
            for (int q = 0; q < 4; ++q) {
                f32x4 wvv = *(const f32x4*)((const char*)w3t + m * 128 + hi * 64 + q * 16);
#pragma unroll
                for (int i = 0; i < 4; ++i)
                    ssum = fmaf(fmaxf(acc[m].s[q * 4 + i], 0.0f), wvv[i], ssum);
            }
        ssum += __shfl_xor(ssum, 32, 64);
        if (hi == 0) {
            const float o = ssum + b3v;
            atomicAdd(outg + (size_t)b * kT + tg, o * psv * (1.0f / 14.0f));
        }
    }
}

} // namespace

extern "C" void kernel_launch(void* const* d_in, const int* in_sizes, int n_in,
                              void* d_out, int out_size, void* d_ws, size_t ws_size,
                              hipStream_t stream) {
    (void)in_sizes; (void)n_in; (void)d_ws; (void)ws_size; (void)out_size;
    const float* pg  = (const float*)d_in[0];
    // d_in[1] = z (unused by the reference)
    const float* cg  = (const float*)d_in[2];
    const float* psg = (const float*)d_in[3];
    const float* W0g = (const float*)d_in[4];
    const float* b0g = (const float*)d_in[5];
    const float* W1g = (const float*)d_in[6];
    const float* b1g = (const float*)d_in[7];
    const float* W2g = (const float*)d_in[8];
    const float* b2g = (const float*)d_in[9];
    const float* W3g = (const float*)d_in[10];
    const float* b3g = (const float*)d_in[11];
    float* outg = (float*)d_out;

    (void)hipMemsetAsync(d_out, 0, (size_t)2 * kT * sizeof(float), stream);
    (void)hipFuncSetAttribute(reinterpret_cast<const void*>(&ptf_kernel),
                              hipFuncAttributeMaxDynamicSharedMemorySize, kSmem);
    ptf_kernel<<<dim3(1792), dim3(512), kSmem, stream>>>(
        pg, cg, psg, W0g, b0g, W1g, b1g, W2g, b2g, W3g, b3g, outg);
}